// Round 1
// baseline (353.845 us; speedup 1.0000x reference)
//
#include <hip/hip_runtime.h>

// PermutationCrossEntropy: preds [B,4,512] f32, targets [B,4] int -> out [B] f32
// out[b] = min over 24 perms sigma of -sum_p logsoftmax(preds[b,p])[targets[b,sigma(p)]]
//
// One wave (64 lanes) per batch element. Each lane holds 8 float4s = 8 elements
// of each of the 4 rows. Butterfly shuffle reductions for max / sum(exp).
// Memory-bound: 256 MB preds read -> ~43 us floor at 6 TB/s.

// Permutations of (0,1,2,3), packed 2 bits per slot: sigma(p) in bits [2p,2p+1].
__device__ __constant__ unsigned char kPermPack[24] = {
    228, 180, 216, 120, 156, 108,   // 0123 0132 0213 0231 0312 0321
    225, 177, 201,  57, 141,  45,   // 1023 1032 1203 1230 1302 1320
    210, 114, 198,  54,  78,  30,   // 2013 2031 2103 2130 2301 2310
    147,  99, 135,  39,  75,  27    // 3012 3021 3102 3120 3201 3210
};

__global__ __launch_bounds__(256) void pce_kernel(
        const float* __restrict__ preds,
        const int* __restrict__ targets,
        float* __restrict__ out,
        int nb) {
    const int lane = threadIdx.x & 63;
    const int wv   = threadIdx.x >> 6;
    const int b    = blockIdx.x * 4 + wv;
    if (b >= nb) return;   // wave-uniform exit

    // ---- coalesced load: 512 float4s per batch element, 8 per lane ----
    const float4* base = reinterpret_cast<const float4*>(preds) + (size_t)b * 512;
    float4 v[8];
#pragma unroll
    for (int j = 0; j < 8; ++j) v[j] = base[lane + 64 * j];
    // row p owns float4 chunks j = 2p, 2p+1  (f = lane + 64*j, row = f>>7)

    // ---- per-row max, then 64-lane butterfly max ----
    float m[4];
#pragma unroll
    for (int p = 0; p < 4; ++p) {
        const float4 a = v[2 * p], c = v[2 * p + 1];
        m[p] = fmaxf(fmaxf(fmaxf(a.x, a.y), fmaxf(a.z, a.w)),
                     fmaxf(fmaxf(c.x, c.y), fmaxf(c.z, c.w)));
    }
#pragma unroll
    for (int off = 32; off; off >>= 1) {
#pragma unroll
        for (int p = 0; p < 4; ++p)
            m[p] = fmaxf(m[p], __shfl_xor(m[p], off, 64));
    }

    // ---- sum(exp(x - max)) per row, butterfly add ----
    float s[4];
#pragma unroll
    for (int p = 0; p < 4; ++p) {
        const float4 a = v[2 * p], c = v[2 * p + 1];
        s[p] = __expf(a.x - m[p]) + __expf(a.y - m[p]) +
               __expf(a.z - m[p]) + __expf(a.w - m[p]) +
               __expf(c.x - m[p]) + __expf(c.y - m[p]) +
               __expf(c.z - m[p]) + __expf(c.w - m[p]);
    }
#pragma unroll
    for (int off = 32; off; off >>= 1) {
#pragma unroll
        for (int p = 0; p < 4; ++p)
            s[p] += __shfl_xor(s[p], off, 64);
    }

    float lse[4];
#pragma unroll
    for (int p = 0; p < 4; ++p) lse[p] = m[p] + __logf(s[p]);

    // ---- gather G[p][j] = logp[b,p,t_j]; lane L<16 -> p=L>>2, j=L&3 ----
    // All 64 lanes execute (lanes>=16 duplicate lanes 0..15) so every
    // subsequent __shfl has well-defined active source lanes.
    const int gp = (lane >> 2) & 3;
    const int gj = lane & 3;
    const int t  = targets[(size_t)b * 4 + gj];             // L1-hot
    const float g = preds[(size_t)b * 2048 + gp * 512 + t]  // L1-hot reload
                    - lse[gp];

    // ---- 24 permutation sums (lanes >=24 duplicate perm 0), min-reduce ----
    const int kk = (lane < 24) ? lane : 0;
    const unsigned pack = kPermPack[kk];
    float loss = 0.0f;
#pragma unroll
    for (int p = 0; p < 4; ++p) {
        const int j = (pack >> (2 * p)) & 3;
        loss -= __shfl(g, p * 4 + j, 64);   // ds_bpermute, per-lane source
    }
#pragma unroll
    for (int off = 32; off; off >>= 1)
        loss = fminf(loss, __shfl_xor(loss, off, 64));

    if (lane == 0) out[b] = loss;
}

extern "C" void kernel_launch(void* const* d_in, const int* in_sizes, int n_in,
                              void* d_out, int out_size, void* d_ws, size_t ws_size,
                              hipStream_t stream) {
    const float* preds   = (const float*)d_in[0];
    const int*   targets = (const int*)d_in[1];
    float*       out     = (float*)d_out;
    const int nb = in_sizes[0] / 2048;          // B = elems / (P*C)
    const int blocks = (nb + 3) / 4;            // 4 waves (batch elems) per block
    hipLaunchKernelGGL(pce_kernel, dim3(blocks), dim3(256), 0, stream,
                       preds, targets, out, nb);
}

// Round 2
// 353.583 us; speedup vs baseline: 1.0007x; 1.0007x over previous
//
#include <hip/hip_runtime.h>

// PermutationCrossEntropy: preds [B,4,512] f32, targets [B,4] int -> out [B] f32
// out[b] = min over 24 perms sigma of -sum_p logsoftmax(preds[b,p])[targets[b,sigma(p)]]
//
// One wave per batch element; each 16-lane quarter owns one of the 4 rows
// (32 elements/lane). Row max / sum(exp) reduce in 4 butterfly steps per
// quarter, all quarters in parallel -> 17 DS ops/wave (was 58).
// Memory-bound: 256 MB preds read -> ~43 us floor at 6.3 TB/s.

// Permutations of (0,1,2,3), packed 2 bits per slot: sigma(p) in bits [2p,2p+1].
__device__ __constant__ unsigned char kPermPack[24] = {
    228, 180, 216, 120, 156, 108,   // 0123 0132 0213 0231 0312 0321
    225, 177, 201,  57, 141,  45,   // 1023 1032 1203 1230 1302 1320
    210, 114, 198,  54,  78,  30,   // 2013 2031 2103 2130 2301 2310
    147,  99, 135,  39,  75,  27    // 3012 3021 3102 3120 3201 3210
};

__global__ __launch_bounds__(256) void pce_kernel(
        const float* __restrict__ preds,
        const int* __restrict__ targets,
        float* __restrict__ out,
        int nb) {
    const int lane = threadIdx.x & 63;
    const int wv   = threadIdx.x >> 6;
    const int b    = blockIdx.x * 4 + wv;
    if (b >= nb) return;   // wave-uniform exit

    const int q   = lane >> 4;   // row owned by this quarter-wave
    const int l16 = lane & 15;

    // ---- coalesced load: quarter q reads row q; 8 float4s per lane.
    // Per instruction the wave touches 4 contiguous 256-B segments (1 KiB).
    const float4* base = reinterpret_cast<const float4*>(preds)
                         + (size_t)b * 512 + q * 128 + l16;
    float4 v[8];
#pragma unroll
    for (int j = 0; j < 8; ++j) v[j] = base[16 * j];

    // ---- row max: per-lane tree, then 4-step butterfly within the quarter ----
    float m = fmaxf(fmaxf(v[0].x, v[0].y), fmaxf(v[0].z, v[0].w));
#pragma unroll
    for (int j = 1; j < 8; ++j)
        m = fmaxf(m, fmaxf(fmaxf(v[j].x, v[j].y), fmaxf(v[j].z, v[j].w)));
#pragma unroll
    for (int off = 8; off; off >>= 1)
        m = fmaxf(m, __shfl_xor(m, off, 64));   // xor<16 stays inside quarter

    // ---- sum(exp(x - max)), 4-step butterfly within the quarter ----
    float s = 0.0f;
#pragma unroll
    for (int j = 0; j < 8; ++j)
        s += __expf(v[j].x - m) + __expf(v[j].y - m) +
             __expf(v[j].z - m) + __expf(v[j].w - m);
#pragma unroll
    for (int off = 8; off; off >>= 1)
        s += __shfl_xor(s, off, 64);

    const float lse = m + __logf(s);   // resident in every lane of quarter q

    // ---- gather g = logp[b, q, t_(lane&3)]; lane p*16+j holds G[p][j].
    // targets are wave-uniform; reload is L1/L2-hot (wave just read this row).
    const int t = targets[(size_t)b * 4 + (lane & 3)];
    const float g = preds[(size_t)b * 2048 + q * 512 + t] - lse;

    // ---- 24 permutation sums (lanes >=24 duplicate perm 0) ----
    const int kk = (lane < 24) ? lane : 0;
    const unsigned pack = kPermPack[kk];
    float loss = 0.0f;
#pragma unroll
    for (int p = 0; p < 4; ++p) {
        const int j = (pack >> (2 * p)) & 3;
        loss -= __shfl(g, (p << 4) + j, 64);   // ds_bpermute, per-lane source
    }
    // min over lanes 0..31 covers all 24 perms (32..63 duplicate 0..31's work)
#pragma unroll
    for (int off = 16; off; off >>= 1)
        loss = fminf(loss, __shfl_xor(loss, off, 64));

    if (lane == 0) out[b] = loss;
}

extern "C" void kernel_launch(void* const* d_in, const int* in_sizes, int n_in,
                              void* d_out, int out_size, void* d_ws, size_t ws_size,
                              hipStream_t stream) {
    const float* preds   = (const float*)d_in[0];
    const int*   targets = (const int*)d_in[1];
    float*       out     = (float*)d_out;
    const int nb = in_sizes[0] / 2048;          // B = elems / (P*C)
    const int blocks = (nb + 3) / 4;            // 4 waves (batch elems) per block
    hipLaunchKernelGGL(pce_kernel, dim3(blocks), dim3(256), 0, stream,
                       preds, targets, out, nb);
}